// Round 16
// baseline (153.407 us; speedup 1.0000x reference)
//
#include <hip/hip_runtime.h>

#define LL 8
#define NN 100000
#define HH 128
#define KT 1024
#define BM 32
#define NNHH (NN * HH)

typedef __attribute__((ext_vector_type(4))) float f32x4;
typedef __attribute__((ext_vector_type(8))) short bf16x8;
typedef __attribute__((ext_vector_type(8))) unsigned short u16x8;

__device__ __forceinline__ unsigned short f2bf(float f) {
    unsigned u = __float_as_uint(f);
    unsigned r = ((u >> 16) & 1u) + 0x7fffu;   // RNE
    return (unsigned short)((u + r) >> 16);
}
__device__ __forceinline__ float bf2f(unsigned short s) {
    return __uint_as_float(((unsigned)s) << 16);
}
__device__ __forceinline__ f32x4 ntload4(const float* p) {
    return __builtin_nontemporal_load(reinterpret_cast<const f32x4*>(p));
}

// Pre-pack w_ref (f32 [128 cols][1024 k]) -> bf16 in fragment order:
// wp[(k8*128 + col)*8 + e] = bf16(w_ref[col][k8*8+e]),  k8 = k/8.
__global__ __launch_bounds__(256) void pack_w_kernel(const float* __restrict__ w_ref,
                                                     unsigned short* __restrict__ wp) {
    int gid = blockIdx.x * 256 + threadIdx.x;   // 0..16383
    int col = gid >> 7;
    int k8  = gid & 127;
    const float* s = w_ref + (size_t)col * KT + (size_t)k8 * 8;
    float4 v0 = *reinterpret_cast<const float4*>(s);
    float4 v1 = *reinterpret_cast<const float4*>(s + 4);
    u16x8 p;
    p[0] = f2bf(v0.x); p[1] = f2bf(v0.y); p[2] = f2bf(v0.z); p[3] = f2bf(v0.w);
    p[4] = f2bf(v1.x); p[5] = f2bf(v1.y); p[6] = f2bf(v1.z); p[7] = f2bf(v1.w);
    *reinterpret_cast<u16x8*>(wp + (size_t)(k8 * 128 + col) * 8) = p;
}

// r9 structure with a TRANSPOSED wave split to halve LDS read amplification:
// 8 waves = 2 node-groups (wn) x 4 col-groups (wc). Wave (wn,wc) computes
// nodes [wn*16,+16) x cols [wc*32,+32) -> A-fragment reads per wave per step
// drop 8 -> 4 ds_read_b128 (LDS traffic per CU-step 144KB -> 80KB, which the
// step-budget audit identified as the ~1750cyc/step residual). B: single
// register set per step, issued right after the MFMAs (barrier + next step's
// loads/convert give L2-latency cover). Everything else identical to r9:
// A depth-3 register prefetch, lgkm-only barriers, NT loads/stores, 8 layer-
// resident bf16 LDS tiles, epilogue sx/softmax/weighted-sum from LDS.
__global__ __launch_bounds__(512, 2)
void gamlp_main(const float* __restrict__ xs,
                const unsigned short* __restrict__ wp,
                const float* __restrict__ b_ref,
                const float* __restrict__ w_att,
                const float* __restrict__ b_att_p,
                const float* __restrict__ alpha_p,
                float* __restrict__ out)
{
    __shared__ unsigned short A_lds[LL][BM * 128];  // 8 x 8KB = 64KB, XOR-swizzled slots
    __shared__ float sjk_lds[BM][4];

    const int tid  = threadIdx.x;
    const int lane = tid & 63;
    const int wave = tid >> 6;      // 0..7
    const int wn   = wave >> 2;     // node-group 0..1
    const int wc   = wave & 3;      // col-group 0..3
    const int colq = lane & 15;
    const int kq   = lane >> 4;
    const int n0   = blockIdx.x * BM;

    const float alpha = *alpha_p;
    const float batt  = *b_att_p;

    // ---- staging map: thread covers (row = tid>>4 in 0..31, 16B slot = tid&15) ----
    const int slot = tid & 15;
    const int row  = tid >> 4;
    const float* src = xs + (size_t)(n0 + row) * HH + slot * 8;
    const int doff = row * 128 + ((slot ^ (row & 15)) * 8);

    // wa_x slice for this thread's k-slot (f32)
    const f32x4 wax0 = *reinterpret_cast<const f32x4*>(w_att + HH + slot * 8);
    const f32x4 wax1 = *reinterpret_cast<const f32x4*>(w_att + HH + slot * 8 + 4);

    // ---- B fragment pointers (packed bf16, L2-resident); wave covers 32 cols ----
    const unsigned short* pB0 = wp + (size_t)(wc * 32 + colq) * 8;
    const unsigned short* pB1 = pB0 + 128;      // +16 cols

    const float wr0 = w_att[wc * 32 + colq],  wr1 = w_att[wc * 32 + 16 + colq];
    const float br0 = b_ref[wc * 32 + colq],  br1 = b_ref[wc * 32 + 16 + colq];

    f32x4 acc[2];
    acc[0] = (f32x4){0, 0, 0, 0};
    acc[1] = (f32x4){0, 0, 0, 0};

    f32x4 pf[3][2];
    bf16x8 B[4][2];     // single B set: 4 c-chunks x 2 col-halves of this wave

#define ISSUE_B(STEP) do {                                                       \
    const int k8_ = (STEP) * 16;                                                 \
    _Pragma("unroll")                                                            \
    for (int c_ = 0; c_ < 4; c_++) {                                             \
        B[c_][0] = *reinterpret_cast<const bf16x8*>(                             \
            pB0 + (size_t)(k8_ + c_ * 4 + kq) * 1024);                           \
        B[c_][1] = *reinterpret_cast<const bf16x8*>(                             \
            pB1 + (size_t)(k8_ + c_ * 4 + kq) * 1024);                           \
    }                                                                            \
} while (0)

#define LOADS(SET, LAY) do {                                                     \
    const size_t g_ = (size_t)(LAY) * NNHH;                                      \
    pf[SET][0] = ntload4(src + g_);                                              \
    pf[SET][1] = ntload4(src + g_ + 4);                                          \
} while (0)

// pure convert + LDS write (sx lives in the epilogue)
#define CONVERT_WRITE(SET, LAY) do {                                             \
    u16x8 pk_;                                                                   \
    _Pragma("unroll")                                                            \
    for (int e_ = 0; e_ < 4; e_++) {                                             \
        pk_[e_]   = f2bf(pf[SET][0][e_]);                                        \
        pk_[e_+4] = f2bf(pf[SET][1][e_]);                                        \
    }                                                                            \
    *reinterpret_cast<u16x8*>(&A_lds[LAY][doff]) = pk_;                          \
} while (0)

#define LGKM_BARRIER() do {                                                      \
    asm volatile("s_waitcnt lgkmcnt(0)" ::: "memory");                           \
    __builtin_amdgcn_s_barrier();                                                \
} while (0)

    // ---- prologue: B(0) first; 3 A-layers in flight; convert layer 0 ----
    ISSUE_B(0);
    LOADS(0, 0);
    LOADS(1, 1);
    LOADS(2, 2);
    CONVERT_WRITE(0, 0);
    LGKM_BARRIER();

    // ---- main loop: 8 steps (step == layer), fully unrolled ----
    #pragma unroll
    for (int s = 0; s < 8; s++) {
        // (1) A loads: depth-3 register pipeline
        if (s + 3 < 8) LOADS((s + 3) % 3, s + 3);
        // (2) convert + ds_write layer s+1 (its loads issued 2 steps ago)
        if (s + 1 < 8) CONVERT_WRITE((s + 1) % 3, s + 1);
        // (3) MFMA on layer s: this wave's 16 rows only (4 ds_read_b128)
        #pragma unroll
        for (int c = 0; c < 4; c++) {
            const int r = wn * 16 + colq;     // row&15 == colq -> swizzle ^colq
            bf16x8 af = *reinterpret_cast<const bf16x8*>(
                &A_lds[s][r * 128 + (((c * 4 + kq) ^ colq) * 8)]);
            acc[0] = __builtin_amdgcn_mfma_f32_16x16x32_bf16(af, B[c][0], acc[0], 0, 0, 0);
            acc[1] = __builtin_amdgcn_mfma_f32_16x16x32_bf16(af, B[c][1], acc[1], 0, 0, 0);
        }
        // (4) issue B(s+1): barrier + next step's loads/convert cover L2 latency
        if (s < 7) {
            ISSUE_B(s + 1);
            LGKM_BARRIER();
        }
    }

    // ---- sjk: sum over this wave's 32 cols of prelu(jk + b_ref) * wa_ref ----
    // D layout: col = wc*32 + n*16 + colq, node = wn*16 + kq*4 + r
    {
        float sr[4];
        #pragma unroll
        for (int r = 0; r < 4; r++) {
            float v0 = acc[0][r] + br0;  v0 = (v0 >= 0.f) ? v0 : alpha * v0;
            float v1 = acc[1][r] + br1;  v1 = (v1 >= 0.f) ? v1 : alpha * v1;
            float sv = v0 * wr0 + v1 * wr1;
            sv += __shfl_xor(sv, 1);
            sv += __shfl_xor(sv, 2);
            sv += __shfl_xor(sv, 4);
            sv += __shfl_xor(sv, 8);
            sr[r] = sv;
        }
        if (colq == 0) {
            #pragma unroll
            for (int r = 0; r < 4; r++)
                sjk_lds[wn * 16 + kq * 4 + r][wc] = sr[r];
        }
    }
    __syncthreads();

    // ---- epilogue: sx from LDS bf16 tiles (batched butterfly), softmax,
    //      weighted sum. Thread handles (node = row, slot); xs NOT re-read. ----
    {
        const int node = row;
        const int boff = node * 128 + ((slot ^ (node & 15)) * 8);
        // pass 1: per-layer partial dots (independent -> ILP)
        float sx[LL];
        #pragma unroll
        for (int l = 0; l < LL; l++) {
            u16x8 v = *reinterpret_cast<const u16x8*>(&A_lds[l][boff]);
            float d = 0.f;
            #pragma unroll
            for (int e = 0; e < 4; e++)
                d += bf2f(v[e]) * wax0[e] + bf2f(v[e + 4]) * wax1[e];
            sx[l] = d;
        }
        // batched butterfly over the 16-slot group: 4 levels x 8 layers, ILP 8
        #pragma unroll
        for (int mser = 1; mser <= 8; mser <<= 1) {
            #pragma unroll
            for (int l = 0; l < LL; l++) sx[l] += __shfl_xor(sx[l], mser);
        }
        float sjk = sjk_lds[node][0] + sjk_lds[node][1] + sjk_lds[node][2] + sjk_lds[node][3];
        float sc[LL], mx = 0.f;
        #pragma unroll
        for (int l = 0; l < LL; l++) {
            float sv = fmaxf(sjk + sx[l] + batt, 0.f);
            sc[l] = sv;
            mx = fmaxf(mx, sv);
        }
        float den = 0.f;
        #pragma unroll
        for (int l = 0; l < LL; l++) { sc[l] = __expf(sc[l] - mx); den += sc[l]; }
        float inv = 1.f / den;
        // pass 2: weighted sum
        f32x4 o0 = (f32x4){0.f, 0.f, 0.f, 0.f};
        f32x4 o1 = (f32x4){0.f, 0.f, 0.f, 0.f};
        #pragma unroll
        for (int l = 0; l < LL; l++) {
            u16x8 v = *reinterpret_cast<const u16x8*>(&A_lds[l][boff]);
            float wl = sc[l] * inv;
            #pragma unroll
            for (int e = 0; e < 4; e++) {
                o0[e] += wl * bf2f(v[e]);
                o1[e] += wl * bf2f(v[e + 4]);
            }
        }
        float* op = out + (size_t)(n0 + node) * HH + slot * 8;
        __builtin_nontemporal_store(o0, reinterpret_cast<f32x4*>(op));
        __builtin_nontemporal_store(o1, reinterpret_cast<f32x4*>(op + 4));
    }
#undef ISSUE_B
#undef LOADS
#undef CONVERT_WRITE
#undef LGKM_BARRIER
}

extern "C" void kernel_launch(void* const* d_in, const int* in_sizes, int n_in,
                              void* d_out, int out_size, void* d_ws, size_t ws_size,
                              hipStream_t stream) {
    const float* xs     = (const float*)d_in[0];
    const float* w_ref  = (const float*)d_in[1];
    const float* b_ref  = (const float*)d_in[2];
    const float* w_att  = (const float*)d_in[3];
    const float* b_att  = (const float*)d_in[4];
    const float* alpha  = (const float*)d_in[5];
    float* out = (float*)d_out;
    unsigned short* wp = (unsigned short*)d_ws;   // 256 KB packed bf16 weights

    pack_w_kernel<<<64, 256, 0, stream>>>(w_ref, wp);
    const int grid = NN / BM;                     // 3125, exact
    gamlp_main<<<grid, 512, 0, stream>>>(xs, wp, b_ref, w_att, b_att, alpha, out);
}

// Round 17
// 151.471 us; speedup vs baseline: 1.0128x; 1.0128x over previous
//
#include <hip/hip_runtime.h>

#define LL 8
#define NN 100000
#define HH 128
#define KT 1024
#define BM 32
#define NNHH (NN * HH)

typedef __attribute__((ext_vector_type(4))) float f32x4;
typedef __attribute__((ext_vector_type(8))) short bf16x8;
typedef __attribute__((ext_vector_type(8))) unsigned short u16x8;

__device__ __forceinline__ unsigned short f2bf(float f) {
    unsigned u = __float_as_uint(f);
    unsigned r = ((u >> 16) & 1u) + 0x7fffu;   // RNE
    return (unsigned short)((u + r) >> 16);
}
__device__ __forceinline__ float bf2f(unsigned short s) {
    return __uint_as_float(((unsigned)s) << 16);
}
__device__ __forceinline__ f32x4 ntload4(const float* p) {
    return __builtin_nontemporal_load(reinterpret_cast<const f32x4*>(p));
}

// Pre-pack w_ref (f32 [128 cols][1024 k]) -> bf16 in fragment order:
// wp[(k8*128 + col)*8 + e] = bf16(w_ref[col][k8*8+e]),  k8 = k/8.
__global__ __launch_bounds__(256) void pack_w_kernel(const float* __restrict__ w_ref,
                                                     unsigned short* __restrict__ wp) {
    int gid = blockIdx.x * 256 + threadIdx.x;   // 0..16383
    int col = gid >> 7;
    int k8  = gid & 127;
    const float* s = w_ref + (size_t)col * KT + (size_t)k8 * 8;
    float4 v0 = *reinterpret_cast<const float4*>(s);
    float4 v1 = *reinterpret_cast<const float4*>(s + 4);
    u16x8 p;
    p[0] = f2bf(v0.x); p[1] = f2bf(v0.y); p[2] = f2bf(v0.z); p[3] = f2bf(v0.w);
    p[4] = f2bf(v1.x); p[5] = f2bf(v1.y); p[6] = f2bf(v1.z); p[7] = f2bf(v1.w);
    *reinterpret_cast<u16x8*>(wp + (size_t)(k8 * 128 + col) * 8) = p;
}

// r9 structure + transposed wave split (2 node-groups x 4 col-groups) with the
// B DOUBLE-BUFFER RESTORED (the r16 confound). Wave (wn,wc): nodes [wn*16,+16)
// x cols [wc*32,+32) -> 4 ds_read_b128/wave/step (half of r9's 8); B(s+1)'s 8
// fragments prefetched during step s's MFMAs (r9's proven pattern). Everything
// else identical to r9: A depth-3 register prefetch, lgkm-only barriers, NT
// loads/stores, 8 layer-resident bf16 LDS tiles, epilogue from LDS, xs ONCE.
__global__ __launch_bounds__(512, 2)
void gamlp_main(const float* __restrict__ xs,
                const unsigned short* __restrict__ wp,
                const float* __restrict__ b_ref,
                const float* __restrict__ w_att,
                const float* __restrict__ b_att_p,
                const float* __restrict__ alpha_p,
                float* __restrict__ out)
{
    __shared__ unsigned short A_lds[LL][BM * 128];  // 8 x 8KB = 64KB, XOR-swizzled slots
    __shared__ float sjk_lds[BM][4];

    const int tid  = threadIdx.x;
    const int lane = tid & 63;
    const int wave = tid >> 6;      // 0..7
    const int wn   = wave >> 2;     // node-group 0..1
    const int wc   = wave & 3;      // col-group 0..3
    const int colq = lane & 15;
    const int kq   = lane >> 4;
    const int n0   = blockIdx.x * BM;

    const float alpha = *alpha_p;
    const float batt  = *b_att_p;

    // ---- staging map: thread covers (row = tid>>4 in 0..31, 16B slot = tid&15) ----
    const int slot = tid & 15;
    const int row  = tid >> 4;
    const float* src = xs + (size_t)(n0 + row) * HH + slot * 8;
    const int doff = row * 128 + ((slot ^ (row & 15)) * 8);

    // wa_x slice for this thread's k-slot (f32)
    const f32x4 wax0 = *reinterpret_cast<const f32x4*>(w_att + HH + slot * 8);
    const f32x4 wax1 = *reinterpret_cast<const f32x4*>(w_att + HH + slot * 8 + 4);

    // ---- B fragment pointers (packed bf16, L2-resident); wave covers 32 cols ----
    const unsigned short* pB0 = wp + (size_t)(wc * 32 + colq) * 8;
    const unsigned short* pB1 = pB0 + 128;      // +16 cols

    const float wr0 = w_att[wc * 32 + colq],  wr1 = w_att[wc * 32 + 16 + colq];
    const float br0 = b_ref[wc * 32 + colq],  br1 = b_ref[wc * 32 + 16 + colq];

    f32x4 acc[2];
    acc[0] = (f32x4){0, 0, 0, 0};
    acc[1] = (f32x4){0, 0, 0, 0};

    f32x4 pf[3][2];
    bf16x8 Bc[4][2], Bn[4][2];   // double-buffered B: 4 c-chunks x 2 col-halves

#define LOADS(SET, LAY) do {                                                     \
    const size_t g_ = (size_t)(LAY) * NNHH;                                      \
    pf[SET][0] = ntload4(src + g_);                                              \
    pf[SET][1] = ntload4(src + g_ + 4);                                          \
} while (0)

// pure convert + LDS write (sx lives in the epilogue)
#define CONVERT_WRITE(SET, LAY) do {                                             \
    u16x8 pk_;                                                                   \
    _Pragma("unroll")                                                            \
    for (int e_ = 0; e_ < 4; e_++) {                                             \
        pk_[e_]   = f2bf(pf[SET][0][e_]);                                        \
        pk_[e_+4] = f2bf(pf[SET][1][e_]);                                        \
    }                                                                            \
    *reinterpret_cast<u16x8*>(&A_lds[LAY][doff]) = pk_;                          \
} while (0)

#define LGKM_BARRIER() do {                                                      \
    asm volatile("s_waitcnt lgkmcnt(0)" ::: "memory");                           \
    __builtin_amdgcn_s_barrier();                                                \
} while (0)

    // ---- B double-buffer: preload step 0's fragments ----
    #pragma unroll
    for (int c = 0; c < 4; c++) {
        Bc[c][0] = *reinterpret_cast<const bf16x8*>(pB0 + (size_t)(c * 4 + kq) * 1024);
        Bc[c][1] = *reinterpret_cast<const bf16x8*>(pB1 + (size_t)(c * 4 + kq) * 1024);
    }

    // ---- prologue: 3 layers of loads in flight, convert layer 0 ----
    LOADS(0, 0);
    LOADS(1, 1);
    LOADS(2, 2);
    CONVERT_WRITE(0, 0);
    LGKM_BARRIER();

    // ---- main loop: 8 steps (step == layer), fully unrolled ----
    #pragma unroll
    for (int s = 0; s < 8; s++) {
        if (s + 3 < 8) LOADS((s + 3) % 3, s + 3);
        if (s + 1 < 8) CONVERT_WRITE((s + 1) % 3, s + 1);
        // prefetch next step's B fragments (in flight during MFMAs)
        if (s < 7) {
            const int k8n = (s + 1) * 16;
            #pragma unroll
            for (int c = 0; c < 4; c++) {
                Bn[c][0] = *reinterpret_cast<const bf16x8*>(pB0 + (size_t)(k8n + c * 4 + kq) * 1024);
                Bn[c][1] = *reinterpret_cast<const bf16x8*>(pB1 + (size_t)(k8n + c * 4 + kq) * 1024);
            }
        }
        // MFMA on layer s: this wave's 16 rows only (4 ds_read_b128)
        #pragma unroll
        for (int c = 0; c < 4; c++) {
            const int r = wn * 16 + colq;
            bf16x8 af = *reinterpret_cast<const bf16x8*>(
                &A_lds[s][r * 128 + (((c * 4 + kq) ^ colq) * 8)]);
            acc[0] = __builtin_amdgcn_mfma_f32_16x16x32_bf16(af, Bc[c][0], acc[0], 0, 0, 0);
            acc[1] = __builtin_amdgcn_mfma_f32_16x16x32_bf16(af, Bc[c][1], acc[1], 0, 0, 0);
        }
        #pragma unroll
        for (int c = 0; c < 4; c++) { Bc[c][0] = Bn[c][0]; Bc[c][1] = Bn[c][1]; }
        if (s < 7) LGKM_BARRIER();
    }

    // ---- sjk: sum over this wave's 32 cols of prelu(jk + b_ref) * wa_ref ----
    // D layout: col = wc*32 + {0,16} + colq, node = wn*16 + kq*4 + r
    {
        float sr[4];
        #pragma unroll
        for (int r = 0; r < 4; r++) {
            float v0 = acc[0][r] + br0;  v0 = (v0 >= 0.f) ? v0 : alpha * v0;
            float v1 = acc[1][r] + br1;  v1 = (v1 >= 0.f) ? v1 : alpha * v1;
            float sv = v0 * wr0 + v1 * wr1;
            sv += __shfl_xor(sv, 1);
            sv += __shfl_xor(sv, 2);
            sv += __shfl_xor(sv, 4);
            sv += __shfl_xor(sv, 8);
            sr[r] = sv;
        }
        if (colq == 0) {
            #pragma unroll
            for (int r = 0; r < 4; r++)
                sjk_lds[wn * 16 + kq * 4 + r][wc] = sr[r];
        }
    }
    __syncthreads();

    // ---- epilogue: sx from LDS bf16 tiles (batched butterfly), softmax,
    //      weighted sum. Thread handles (node = row, slot); xs NOT re-read. ----
    {
        const int node = row;
        const int boff = node * 128 + ((slot ^ (node & 15)) * 8);
        float sx[LL];
        #pragma unroll
        for (int l = 0; l < LL; l++) {
            u16x8 v = *reinterpret_cast<const u16x8*>(&A_lds[l][boff]);
            float d = 0.f;
            #pragma unroll
            for (int e = 0; e < 4; e++)
                d += bf2f(v[e]) * wax0[e] + bf2f(v[e + 4]) * wax1[e];
            sx[l] = d;
        }
        #pragma unroll
        for (int mser = 1; mser <= 8; mser <<= 1) {
            #pragma unroll
            for (int l = 0; l < LL; l++) sx[l] += __shfl_xor(sx[l], mser);
        }
        float sjk = sjk_lds[node][0] + sjk_lds[node][1] + sjk_lds[node][2] + sjk_lds[node][3];
        float sc[LL], mx = 0.f;
        #pragma unroll
        for (int l = 0; l < LL; l++) {
            float sv = fmaxf(sjk + sx[l] + batt, 0.f);
            sc[l] = sv;
            mx = fmaxf(mx, sv);
        }
        float den = 0.f;
        #pragma unroll
        for (int l = 0; l < LL; l++) { sc[l] = __expf(sc[l] - mx); den += sc[l]; }
        float inv = 1.f / den;
        f32x4 o0 = (f32x4){0.f, 0.f, 0.f, 0.f};
        f32x4 o1 = (f32x4){0.f, 0.f, 0.f, 0.f};
        #pragma unroll
        for (int l = 0; l < LL; l++) {
            u16x8 v = *reinterpret_cast<const u16x8*>(&A_lds[l][boff]);
            float wl = sc[l] * inv;
            #pragma unroll
            for (int e = 0; e < 4; e++) {
                o0[e] += wl * bf2f(v[e]);
                o1[e] += wl * bf2f(v[e + 4]);
            }
        }
        float* op = out + (size_t)(n0 + node) * HH + slot * 8;
        __builtin_nontemporal_store(o0, reinterpret_cast<f32x4*>(op));
        __builtin_nontemporal_store(o1, reinterpret_cast<f32x4*>(op + 4));
    }
#undef LOADS
#undef CONVERT_WRITE
#undef LGKM_BARRIER
}

extern "C" void kernel_launch(void* const* d_in, const int* in_sizes, int n_in,
                              void* d_out, int out_size, void* d_ws, size_t ws_size,
                              hipStream_t stream) {
    const float* xs     = (const float*)d_in[0];
    const float* w_ref  = (const float*)d_in[1];
    const float* b_ref  = (const float*)d_in[2];
    const float* w_att  = (const float*)d_in[3];
    const float* b_att  = (const float*)d_in[4];
    const float* alpha  = (const float*)d_in[5];
    float* out = (float*)d_out;
    unsigned short* wp = (unsigned short*)d_ws;   // 256 KB packed bf16 weights

    pack_w_kernel<<<64, 256, 0, stream>>>(w_ref, wp);
    const int grid = NN / BM;                     // 3125, exact
    gamlp_main<<<grid, 512, 0, stream>>>(xs, wp, b_ref, w_att, b_att, alpha, out);
}